// Round 3
// baseline (166.644 us; speedup 1.0000x reference)
//
#include <hip/hip_runtime.h>
#include <hip/hip_cooperative_groups.h>
#include <math.h>

namespace cg = cooperative_groups;

#define NBLK 512   // 512 blocks x 4 waves x 2 rows = 4096 rows

// ws (uint cells): [0]=raw-max key, [1]=filtered-min key, [2]=raw-min key
// monotone order-preserving float->uint key
__device__ __forceinline__ unsigned f2key(float f){
  unsigned b = __float_as_uint(f);
  return (b & 0x80000000u) ? ~b : (b | 0x80000000u);
}
__device__ __forceinline__ float key2f(unsigned k){
  unsigned b = (k & 0x80000000u) ? (k ^ 0x80000000u) : ~k;
  return __uint_as_float(b);
}

__device__ __forceinline__ float wred_max(float x){
  #pragma unroll
  for (int m = 32; m; m >>= 1) x = fmaxf(x, __shfl_xor(x, m, 64));
  return x;
}
__device__ __forceinline__ float wred_min(float x){
  #pragma unroll
  for (int m = 32; m; m >>= 1) x = fminf(x, __shfl_xor(x, m, 64));
  return x;
}
__device__ __forceinline__ void wred_sum2(float& a, float& b){
  #pragma unroll
  for (int m = 32; m; m >>= 1){
    float ta = __shfl_xor(a, m, 64);
    float tb = __shfl_xor(b, m, 64);
    a += ta; b += tb;
  }
}

// sum of 1/(t+r[i]) over 4 elements with a single v_rcp
__device__ __forceinline__ void grp4(const float* r, float t, float& acc){
  float a0 = t + r[0], a1 = t + r[1], a2 = t + r[2], a3 = t + r[3];
  float m01 = a0 * a1, m23 = a2 * a3;
  float num = fmaf(m01, a2 + a3, m23 * (a0 + a1));
  acc = fmaf(num, __builtin_amdgcn_rcpf(m01 * m23), acc);
}

__global__ __launch_bounds__(256, 4)
void k_fused(const float* __restrict__ scores, float* __restrict__ out,
             unsigned* __restrict__ ws){
  const int wid  = threadIdx.x >> 6;
  const int lane = threadIdx.x & 63;
  const int rowA = blockIdx.x * 8 + wid * 2;
  const int rowB = rowA + 1;
  const float4* __restrict__ srcA = (const float4*)(scores + (size_t)rowA * 2048);
  const float4* __restrict__ srcB = (const float4*)(scores + (size_t)rowB * 2048);

  // ---- Phase A: load both rows into registers, min/max partials ----
  float sA[32], sB[32];
  float mx = -INFINITY, fmn = INFINITY, rmn = INFINITY;
  #pragma unroll
  for (int k = 0; k < 8; ++k){
    float4 va = srcA[k * 64 + lane];
    float4 vb = srcB[k * 64 + lane];
    sA[4*k+0] = va.x; sA[4*k+1] = va.y; sA[4*k+2] = va.z; sA[4*k+3] = va.w;
    sB[4*k+0] = vb.x; sB[4*k+1] = vb.y; sB[4*k+2] = vb.z; sB[4*k+3] = vb.w;
    #pragma unroll
    for (int j = 0; j < 4; ++j){
      float x = sA[4*k+j], y = sB[4*k+j];
      mx  = fmaxf(mx, fmaxf(x, y));
      rmn = fminf(rmn, fminf(x, y));
      fmn = fminf(fmn, fminf((x == -INFINITY) ? INFINITY : x,
                             (y == -INFINITY) ? INFINITY : y));
    }
  }
  mx = wred_max(mx); fmn = wred_min(fmn); rmn = wred_min(rmn);
  __shared__ float sm[12];
  if (lane == 0){ sm[wid] = mx; sm[4 + wid] = fmn; sm[8 + wid] = rmn; }
  __syncthreads();
  if (threadIdx.x == 0){
    float a = fmaxf(fmaxf(sm[0], sm[1]), fmaxf(sm[2], sm[3]));
    float b = fminf(fminf(sm[4], sm[5]), fminf(sm[6], sm[7]));
    float c = fminf(fminf(sm[8], sm[9]), fminf(sm[10], sm[11]));
    atomicMax(&ws[0], f2key(a));
    atomicMin(&ws[1], f2key(b));
    atomicMin(&ws[2], f2key(c));
  }

  cg::this_grid().sync();

  // ---- Phase B: constants (duplicated per thread, cheap) ----
  float max_s = key2f(__hip_atomic_load(&ws[0], __ATOMIC_RELAXED, __HIP_MEMORY_SCOPE_AGENT));
  float min_s = key2f(__hip_atomic_load(&ws[1], __ATOMIC_RELAXED, __HIP_MEMORY_SCOPE_AGENT));
  float rmin  = key2f(__hip_atomic_load(&ws[2], __ATOMIC_RELAXED, __HIP_MEMORY_SCOPE_AGENT));
  float filled = min_s - (max_s - min_s);
  float lo = (rmin == -INFINITY) ? filled : min_s;
  float hi = max_s;
  float cmax = fmaxf(fmaxf(lo * lo, (lo - 1.f) * (lo - 1.f)),
                     fmaxf(hi * hi, (hi - 1.f) * (hi - 1.f)));
  float invX = 1.0f / (cmax * 0.1f);           // 1/(Cmax*EPS)
  float cc = 1.4426950408889634f * invX;       // log2(e)/(Cmax*EPS)
  const float cA = 2.0f * cc, cB = -cc;

  // transform registers in place: s -> r = exp2(s*cA + cB) = G1/G0
  #pragma unroll
  for (int k = 0; k < 32; ++k){
    float x = sA[k]; if (x == -INFINITY) x = filled;
    sA[k] = __builtin_amdgcn_exp2f(fmaf(x, cA, cB));
    float y = sB[k]; if (y == -INFINITY) y = filled;
    sB[k] = __builtin_amdgcn_exp2f(fmaf(y, cA, cB));
  }

  // ---- Phase C: scalar Sinkhorn, t = v0/v1, P(t) = t * sum 1/(t+r) ----
  float tA = 1.0f, PA = 0.0f, tB = 1.0f, PB = 0.0f;
  int it = 0;
  while (true){
    float accA = 0.f, accB = 0.f;
    #pragma unroll
    for (int g = 0; g < 8; ++g){
      grp4(sA + 4 * g, tA, accA);
      grp4(sB + 4 * g, tB, accB);
    }
    wred_sum2(accA, accB);
    PA = tA * accA; PB = tB * accB;
    if (++it == 50) break;
    float tnA = tA * (2048.0f - PA) * 0.0322580645161f * __builtin_amdgcn_rcpf(PA);
    float tnB = tB * (2048.0f - PB) * 0.0322580645161f * __builtin_amdgcn_rcpf(PB);
    if (fabsf(tnA - tA) <= 1e-7f * tA && fabsf(tnB - tB) <= 1e-7f * tB) break;
    tA = tnA; tB = tnB;
  }

  // ---- Epilogue: A_i = (K*t/P) * 1/(t+r_i) ----
  const float c0A = 64.0f * tA * __builtin_amdgcn_rcpf(PA);
  const float c0B = 64.0f * tB * __builtin_amdgcn_rcpf(PB);
  float4* __restrict__ dA = (float4*)(out + (size_t)rowA * 2048);
  float4* __restrict__ dB = (float4*)(out + (size_t)rowB * 2048);
  #pragma unroll
  for (int k = 0; k < 8; ++k){
    float4 oa, ob;
    oa.x = c0A * __builtin_amdgcn_rcpf(tA + sA[4*k+0]);
    oa.y = c0A * __builtin_amdgcn_rcpf(tA + sA[4*k+1]);
    oa.z = c0A * __builtin_amdgcn_rcpf(tA + sA[4*k+2]);
    oa.w = c0A * __builtin_amdgcn_rcpf(tA + sA[4*k+3]);
    ob.x = c0B * __builtin_amdgcn_rcpf(tB + sB[4*k+0]);
    ob.y = c0B * __builtin_amdgcn_rcpf(tB + sB[4*k+1]);
    ob.z = c0B * __builtin_amdgcn_rcpf(tB + sB[4*k+2]);
    ob.w = c0B * __builtin_amdgcn_rcpf(tB + sB[4*k+3]);
    dA[k * 64 + lane] = oa;
    dB[k * 64 + lane] = ob;
  }
}

extern "C" void kernel_launch(void* const* d_in, const int* in_sizes, int n_in,
                              void* d_out, int out_size, void* d_ws, size_t ws_size,
                              hipStream_t stream) {
  const float* scores = (const float*)d_in[0];
  float* out = (float*)d_out;
  unsigned* ws = (unsigned*)d_ws;

  // init atomic cells: max key -> 0x00000000, min keys -> 0xFFFFFFFF
  hipMemsetAsync(ws,     0x00, 4, stream);
  hipMemsetAsync(ws + 1, 0xFF, 8, stream);

  void* args[] = { (void*)&scores, (void*)&out, (void*)&ws };
  hipLaunchCooperativeKernel((void*)k_fused, dim3(NBLK), dim3(256), args, 0, stream);
}

// Round 4
// 91.713 us; speedup vs baseline: 1.8170x; 1.8170x over previous
//
#include <hip/hip_runtime.h>
#include <math.h>

// ws layout (floats):
// [0..1024)      per-block raw max partials
// [1024..2048)   per-block filtered min (-inf -> +inf) partials
// [2048..3072)   per-block raw min partials
// [3072]         filled value (-inf replacement)
// [3073]         cA = 2*log2(e)/(Cmax*EPS)   (r = exp2(s*cA + cB))
// [3074]         cB = -log2(e)/(Cmax*EPS)
#define NB_MM   1024
#define WS_MAX  0
#define WS_FMIN 1024
#define WS_RMIN 2048
#define WS_CONST 3072

__device__ __forceinline__ float wred_max(float x){
  #pragma unroll
  for (int m = 32; m; m >>= 1) x = fmaxf(x, __shfl_xor(x, m, 64));
  return x;
}
__device__ __forceinline__ float wred_min(float x){
  #pragma unroll
  for (int m = 32; m; m >>= 1) x = fminf(x, __shfl_xor(x, m, 64));
  return x;
}
__device__ __forceinline__ float wred_sum(float x){
  #pragma unroll
  for (int m = 32; m; m >>= 1) x += __shfl_xor(x, m, 64);
  return x;
}

// Pass 1: per-block {raw max, filtered min, raw min} over all scores.
__global__ __launch_bounds__(256) void k_minmax(const float4* __restrict__ s4,
                                                int n4, float* __restrict__ ws){
  int tid = blockIdx.x * 256 + threadIdx.x;
  float mx = -INFINITY, fmn = INFINITY, rmn = INFINITY;
  for (int i = tid; i < n4; i += NB_MM * 256){
    float4 v = s4[i];
    float c[4] = {v.x, v.y, v.z, v.w};
    #pragma unroll
    for (int j = 0; j < 4; ++j){
      float s = c[j];
      mx  = fmaxf(mx, s);
      rmn = fminf(rmn, s);
      fmn = fminf(fmn, (s == -INFINITY) ? INFINITY : s);
    }
  }
  mx = wred_max(mx); fmn = wred_min(fmn); rmn = wred_min(rmn);
  __shared__ float sm[12];
  int w = threadIdx.x >> 6;
  if ((threadIdx.x & 63) == 0){ sm[w] = mx; sm[4 + w] = fmn; sm[8 + w] = rmn; }
  __syncthreads();
  if (threadIdx.x == 0){
    ws[WS_MAX  + blockIdx.x] = fmaxf(fmaxf(sm[0], sm[1]), fmaxf(sm[2], sm[3]));
    ws[WS_FMIN + blockIdx.x] = fminf(fminf(sm[4], sm[5]), fminf(sm[6], sm[7]));
    ws[WS_RMIN + blockIdx.x] = fminf(fminf(sm[8], sm[9]), fminf(sm[10], sm[11]));
  }
}

// Pass 2: fold partials -> filled value and exp2 coefficients.
// Cmax = max over data of max(s^2,(s-1)^2); convex => attained at extremes.
__global__ __launch_bounds__(256) void k_finalize(float* __restrict__ ws){
  int t = threadIdx.x;
  float mx = -INFINITY, fmn = INFINITY, rmn = INFINITY;
  #pragma unroll
  for (int j = 0; j < NB_MM / 256; ++j){
    mx  = fmaxf(mx,  ws[WS_MAX  + t + 256 * j]);
    fmn = fminf(fmn, ws[WS_FMIN + t + 256 * j]);
    rmn = fminf(rmn, ws[WS_RMIN + t + 256 * j]);
  }
  mx = wred_max(mx); fmn = wred_min(fmn); rmn = wred_min(rmn);
  __shared__ float sm[12];
  int w = t >> 6;
  if ((t & 63) == 0){ sm[w] = mx; sm[4 + w] = fmn; sm[8 + w] = rmn; }
  __syncthreads();
  if (t == 0){
    float max_s = fmaxf(fmaxf(sm[0], sm[1]), fmaxf(sm[2], sm[3]));
    float min_s = fminf(fminf(sm[4], sm[5]), fminf(sm[6], sm[7]));
    float rmin  = fminf(fminf(sm[8], sm[9]), fminf(sm[10], sm[11]));
    float filled = min_s - (max_s - min_s);
    float lo = (rmin == -INFINITY) ? filled : min_s;
    float hi = max_s;
    float cmax = fmaxf(fmaxf(lo * lo, (lo - 1.f) * (lo - 1.f)),
                       fmaxf(hi * hi, (hi - 1.f) * (hi - 1.f)));
    float invX = 1.0f / (cmax * 0.1f);           // 1/(Cmax*EPS)
    float c = 1.4426950408889634f * invX;        // log2(e)/(Cmax*EPS)
    ws[WS_CONST]     = filled;
    ws[WS_CONST + 1] = 2.0f * c;                 // cA
    ws[WS_CONST + 2] = -c;                       // cB
  }
}

// Pass 3: one wave per row.
// r_i = G1/G0 = exp2(s*cA + cB).  Scalar state t = v0/v1 (t0 = 1).
//   acc = sum_i 1/(t + r_i)   (4-way batched reciprocals)
//   P   = t*acc;  fixed point is P = K;  t' = t*(K/(n-K))*(n-P)/P
// Contraction factor ~0.03 for this data => converges ~1.5 digits/iter;
// exit tol 1e-6*t (> 1 ulp of t, so a 1-ulp limit cycle still exits).
// Output A_i = (K*t/P) * 1/(t + r_i) using the final iteration's (t,P).
__global__ __launch_bounds__(256) void k_sinkhorn(const float* __restrict__ scores,
                                                  float* __restrict__ out,
                                                  const float* __restrict__ cons){
  const float filled = cons[0];
  const float cA = cons[1], cB = cons[2];
  const int row  = blockIdx.x * 4 + (threadIdx.x >> 6);
  const int lane = threadIdx.x & 63;
  const float4* __restrict__ src = (const float4*)(scores + (size_t)row * 2048);

  float r[32];
  #pragma unroll
  for (int k = 0; k < 8; ++k){
    float4 v = src[k * 64 + lane];
    float c[4] = {v.x, v.y, v.z, v.w};
    #pragma unroll
    for (int j = 0; j < 4; ++j){
      float s = c[j];
      if (s == -INFINITY) s = filled;
      r[k * 4 + j] = __builtin_amdgcn_exp2f(fmaf(s, cA, cB));
    }
  }

  float t = 1.0f, P = 0.0f;
  int it = 0;
  while (true){
    float acc0 = 0.f, acc1 = 0.f;
    #pragma unroll
    for (int g = 0; g < 8; g += 2){
      {
        float a0 = t + r[4*g+0], a1 = t + r[4*g+1];
        float a2 = t + r[4*g+2], a3 = t + r[4*g+3];
        float m01 = a0 * a1, m23 = a2 * a3;
        float num = fmaf(m01, a2 + a3, m23 * (a0 + a1));
        acc0 = fmaf(num, __builtin_amdgcn_rcpf(m01 * m23), acc0);
      }
      {
        float a0 = t + r[4*g+4], a1 = t + r[4*g+5];
        float a2 = t + r[4*g+6], a3 = t + r[4*g+7];
        float m01 = a0 * a1, m23 = a2 * a3;
        float num = fmaf(m01, a2 + a3, m23 * (a0 + a1));
        acc1 = fmaf(num, __builtin_amdgcn_rcpf(m01 * m23), acc1);
      }
    }
    float acc = wred_sum(acc0 + acc1);
    P = t * acc;
    if (++it == 50) break;
    float tn = t * (2048.0f - P) * 0.0322580645161f * __builtin_amdgcn_rcpf(P);
    if (fabsf(tn - t) <= 1e-6f * t) break;   // converged: further ref iters are no-ops
    t = tn;
  }

  // Epilogue: A_i = c0 / (t + r_i), batched (1 rcp per 4 outputs):
  // 1/a0 = a1*m23 * rcp(a0*a1*a2*a3), etc. Products in [4e-5, 1.2e4] -> safe.
  const float c0 = 64.0f * t * __builtin_amdgcn_rcpf(P);
  float4* __restrict__ dst = (float4*)(out + (size_t)row * 2048);
  #pragma unroll
  for (int k = 0; k < 8; ++k){
    float a0 = t + r[4*k+0], a1 = t + r[4*k+1];
    float a2 = t + r[4*k+2], a3 = t + r[4*k+3];
    float m01 = a0 * a1, m23 = a2 * a3;
    float e = c0 * __builtin_amdgcn_rcpf(m01 * m23);
    float4 o;
    o.x = a1 * m23 * e;
    o.y = a0 * m23 * e;
    o.z = a3 * m01 * e;
    o.w = a2 * m01 * e;
    dst[k * 64 + lane] = o;
  }
}

extern "C" void kernel_launch(void* const* d_in, const int* in_sizes, int n_in,
                              void* d_out, int out_size, void* d_ws, size_t ws_size,
                              hipStream_t stream) {
  const float* scores = (const float*)d_in[0];
  float* out = (float*)d_out;
  float* ws  = (float*)d_ws;
  const int n4 = in_sizes[0] / 4;

  k_minmax  <<<NB_MM, 256, 0, stream>>>((const float4*)scores, n4, ws);
  k_finalize<<<1,     256, 0, stream>>>(ws);
  k_sinkhorn<<<1024,  256, 0, stream>>>(scores, out, ws + WS_CONST);
}